// Round 5
// baseline (493.558 us; speedup 1.0000x reference)
//
#include <hip/hip_runtime.h>

// Problem dims (fixed by setup_inputs)
#define BN 16      // batch
#define FD 256     // features
#define SH 64      // small h
#define SW 64      // small w
#define BH 512     // big H
#define BW 512     // big W
#define KN 21      // classes
#define SP (SH*SW)   // 4096 small pixels
#define BP (BH*BW)   // 262144 big pixels

#define SEG_BLOCKS 256                 // 65536 threads, 1 px each
#define DOWNX_BLOCKS (BN*3*BH/4)       // 6144: one block = (bc, 4 Y rows)
#define QPARTS 16                      // phase2: 16 parts x 256 px per batch

typedef float f32x4 __attribute__((ext_vector_type(4)));

// ---------------------------------------------------------------------------
// Adjoint bilinear (align_corners=True) weight, f32 (validated r1/r4:
// min distance of X*63/511 to a non-attained integer is 1/511 ~ 2e-3 >>
// f32 error ~4e-6, so floor never crosses; weight error ~3e-8 << 4.9e-4).
__device__ __forceinline__ float adj_w(int big, int small) {
    float t = (float)big * (63.0f / 511.0f);
    int i0 = (int)t;
    float fr = t - (float)i0;
    int i1 = i0 + 1; if (i1 > 63) i1 = 63;
    float w = 0.0f;
    if (i0 == small) w += 1.0f - fr;
    if (i1 == small) w += fr;
    return w;
}

__device__ __forceinline__ void adj_range(int small, int& lo, int& hi) {
    lo = (int)floorf((small - 1) * (511.0f / 63.0f)); if (lo < 0) lo = 0;
    hi = (int)ceilf((small + 1) * (511.0f / 63.0f));  if (hi > 511) hi = 511;
}

// ---------------------------------------------------------------------------
// seg: 1x1 conv + softmax, ONE pixel per thread (identical to r3/r4).
__device__ __forceinline__ void seg_body(int blk, int tid,
                                         const float* __restrict__ fm,
                                         const float* __restrict__ cw,
                                         const float* __restrict__ cb,
                                         float* __restrict__ seg) {
    int gid = blk * 256 + tid;          // 0..65535
    int b   = gid >> 12;                // 4096 px per batch
    int p   = gid & 4095;
    const float* fmb = fm + (size_t)b * FD * SP + p;

    float acc[KN];
#pragma unroll
    for (int k = 0; k < KN; ++k) acc[k] = 0.0f;

#pragma unroll 4
    for (int f = 0; f < FD; ++f) {
        float v = fmb[(size_t)f * SP];   // 256B coalesced per wave
#pragma unroll
        for (int k = 0; k < KN; ++k)
            acc[k] = fmaf(v, cw[k * FD + f], acc[k]);   // cw uniform -> s_load
    }

    float mx = -1e30f;
#pragma unroll
    for (int k = 0; k < KN; ++k) { acc[k] += cb[k]; mx = fmaxf(mx, acc[k]); }
    float s = 0.0f;
#pragma unroll
    for (int k = 0; k < KN; ++k) { acc[k] = expf(acc[k] - mx); s += acc[k]; }
    float inv = 1.0f / s;

    float* segb = seg + (size_t)b * KN * SP + p;
#pragma unroll
    for (int k = 0; k < KN; ++k) segb[(size_t)k * SP] = acc[k] * inv;   // 256B coalesced
}

// downx: tmpA[bc, Y, s] = sum_X W[X,s] * x[bc, Y, X]   (identical to r4)
__device__ __forceinline__ void downx_body(int blk, int tid,
                                           const float* __restrict__ x,
                                           float* __restrict__ tmpA,
                                           float (*rows)[BW]) {
    int bc = blk >> 7;                  // 0..47
    int Y0 = (blk & 127) << 2;          // 4 Y rows per block
    const f32x4* src = (const f32x4*)(x + ((size_t)bc * BH + Y0) * BW);
    f32x4* dst = (f32x4*)&rows[0][0];
    dst[tid]       = src[tid];          // 2048 floats = 512 float4, 2/thread
    dst[tid + 256] = src[tid + 256];
    __syncthreads();

    int s  = tid & 63;
    int yl = tid >> 6;
    int lo, hi; adj_range(s, lo, hi);
    float acc = 0.0f;
    for (int X = lo; X <= hi; ++X) acc = fmaf(adj_w(X, s), rows[yl][X], acc);
    tmpA[((size_t)bc * BH + Y0 + yl) * SW + s] = acc;   // 256B coalesced
}

// Phase 1: seg (blocks [0,256)) runs concurrently with downx (blocks [256,6400)).
// CHANGE vs r4: blocks 0..3 also zero q (1008 floats) — the kernel boundary
// orders this before phase2's atomic accumulation (r3-validated pattern).
__global__ __launch_bounds__(256) void k_phase1(const float* __restrict__ fm,
                                                const float* __restrict__ cw,
                                                const float* __restrict__ cb,
                                                const float* __restrict__ x,
                                                float* __restrict__ seg,
                                                float* __restrict__ tmpA,
                                                float* __restrict__ q) {
    __shared__ float rows[4][BW];       // 8 KB (unused by seg blocks)
    if (blockIdx.x < 4) {
        int i = blockIdx.x * 256 + threadIdx.x;
        if (i < BN * KN * 3) q[i] = 0.0f;
    }
    if (blockIdx.x < SEG_BLOCKS) seg_body(blockIdx.x, threadIdx.x, fm, cw, cb, seg);
    else                         downx_body(blockIdx.x - SEG_BLOCKS, threadIdx.x, x, tmpA, rows);
}

// ---------------------------------------------------------------------------
// Phase 2 (CHANGE vs r4: fuses k_downy + k_q, one dispatch fewer, xd never
// touches HBM). One block per (b, part): 256 pixels of the 64x64 grid.
//   xd[c][j] = sum_Y W[Y,r] * tmpA[(b,c), Y, s]   (into LDS, no k-redundancy)
//   q[b,k,c] += (1/BP) * sum_j seg[b,k,p0+j] * xd[c][j]   (block-reduced, atomic)
// Identical per-element math to the old k_downy (same fmaf order over Y);
// only the q summation order changes (atomic parts), rounding ~1e-7.
__global__ __launch_bounds__(256) void k_phase2(const float* __restrict__ tmpA,
                                                const float* __restrict__ seg,
                                                float* __restrict__ q) {
    int b    = blockIdx.x >> 4;         // 0..15
    int part = blockIdx.x & 15;         // 16 parts x 256 px
    int p0   = part * 256;

    __shared__ float xd[3][256];
    // 768 entries, 3 per thread; within a wave j spans 64 consecutive px ->
    // r uniform, s=0..63 -> 256B coalesced tmpA loads.
    for (int e = threadIdx.x; e < 3 * 256; e += 256) {
        int c = e >> 8;
        int j = e & 255;
        int p = p0 + j;
        int r = p >> 6, s = p & 63;
        const float* base = tmpA + ((size_t)(b * 3 + c) * BH) * SW + s;
        int lo, hi; adj_range(r, lo, hi);
        float acc = 0.0f;
        for (int Y = lo; Y <= hi; ++Y) acc = fmaf(adj_w(Y, r), base[(size_t)Y * SW], acc);
        xd[c][j] = acc;
    }
    __syncthreads();

    // each thread owns pixel j = threadIdx.x; 63 (k,c) partials in registers
    const float* segb = seg + (size_t)b * KN * SP + p0 + threadIdx.x;
    float x0 = xd[0][threadIdx.x], x1 = xd[1][threadIdx.x], x2 = xd[2][threadIdx.x];
    float accq[KN][3];
#pragma unroll
    for (int k = 0; k < KN; ++k) {
        float sv = segb[(size_t)k * SP];    // 1KB coalesced per block per k
        accq[k][0] = sv * x0;
        accq[k][1] = sv * x1;
        accq[k][2] = sv * x2;
    }

    // wave shfl-reduce each of 63 sums, combine 4 waves via LDS, one atomic each
    __shared__ float redq[4][KN * 3];
    int lane = threadIdx.x & 63, w = threadIdx.x >> 6;
#pragma unroll
    for (int k = 0; k < KN; ++k)
#pragma unroll
        for (int c = 0; c < 3; ++c) {
            float v = accq[k][c];
            for (int off = 32; off > 0; off >>= 1) v += __shfl_down(v, off, 64);
            if (lane == 0) redq[w][k * 3 + c] = v;
        }
    __syncthreads();
    if (threadIdx.x < KN * 3) {
        float v = redq[0][threadIdx.x] + redq[1][threadIdx.x]
                + redq[2][threadIdx.x] + redq[3][threadIdx.x];
        atomicAdd(q + (size_t)b * KN * 3 + threadIdx.x, v * (1.0f / (float)BP));
    }
}

// ---------------------------------------------------------------------------
// attn[b,k,p] = sum_c x[b,c,p] * q[b,k,c]; float4, nontemporal stores
// (identical to r0/r3/r4)
__global__ __launch_bounds__(256) void k_attn(const float* __restrict__ x,
                                              const float* __restrict__ q,
                                              float* __restrict__ out) {
    int b   = blockIdx.x >> 8;
    int blk = blockIdx.x & 255;
    int p4  = blk * 256 + threadIdx.x;

    const f32x4* xb = (const f32x4*)(x + (size_t)b * 3 * BP);
    f32x4 x0 = xb[p4];
    f32x4 x1 = xb[BP / 4 + p4];
    f32x4 x2 = xb[2 * (BP / 4) + p4];

    __shared__ float qs[KN * 3];
    if (threadIdx.x < KN * 3) qs[threadIdx.x] = q[(size_t)b * KN * 3 + threadIdx.x];
    __syncthreads();

    f32x4* ob = (f32x4*)(out + (size_t)b * KN * BP) + p4;
#pragma unroll
    for (int k = 0; k < KN; ++k) {
        float q0 = qs[k * 3], q1 = qs[k * 3 + 1], q2 = qs[k * 3 + 2];
        f32x4 r = x0 * q0 + x1 * q1 + x2 * q2;
        __builtin_nontemporal_store(r, ob + (size_t)k * (BP / 4));
    }
}

// ---------------------------------------------------------------------------
extern "C" void kernel_launch(void* const* d_in, const int* in_sizes, int n_in,
                              void* d_out, int out_size, void* d_ws, size_t ws_size,
                              hipStream_t stream) {
    const float* fm = (const float*)d_in[0];   // [16,256,64,64]
    const float* x  = (const float*)d_in[1];   // [16,3,512,512]
    const float* cw = (const float*)d_in[2];   // [21,256]
    const float* cb = (const float*)d_in[3];   // [21]
    float* out = (float*)d_out;                // [16,21,512,512]

    // workspace layout (floats): seg | tmpA | q  (~11.3 MB total; xd gone)
    float* seg  = (float*)d_ws;                       // 16*21*4096
    float* tmpA = seg  + (size_t)BN * KN * SP;        // 16*3*512*64
    float* q    = tmpA + (size_t)BN * 3 * BH * SW;    // 16*21*3

    k_phase1<<<SEG_BLOCKS + DOWNX_BLOCKS, 256, 0, stream>>>(fm, cw, cb, x, seg, tmpA, q);
    k_phase2<<<BN * QPARTS,               256, 0, stream>>>(tmpA, seg, q);
    k_attn  <<<BN * (BP / 1024),          256, 0, stream>>>(x, q, out);
}

// Round 6
// 479.016 us; speedup vs baseline: 1.0304x; 1.0304x over previous
//
#include <hip/hip_runtime.h>

// Problem dims (fixed by setup_inputs)
#define BN 16      // batch
#define FD 256     // features
#define SH 64      // small h
#define SW 64      // small w
#define BH 512     // big H
#define BW 512     // big W
#define KN 21      // classes
#define SP (SH*SW)   // 4096 small pixels
#define BP (BH*BW)   // 262144 big pixels

#define SEG_BLOCKS 256                 // 65536 threads, 1 px each
#define DOWNX_BLOCKS (BN*3*BH/4)       // 6144: one block = (bc, 4 Y rows)
#define QSPLIT 4                       // k_q parallelism: 4 blocks per (b,k)

typedef float f32x4 __attribute__((ext_vector_type(4)));

// ---------------------------------------------------------------------------
// Adjoint bilinear (align_corners=True) weight, f32 (validated r1/r4:
// min distance of X*63/511 to a non-attained integer is 1/511 ~ 2e-3 >>
// f32 error ~4e-6, so floor never crosses; weight error ~3e-8 << 4.9e-4).
__device__ __forceinline__ float adj_w(int big, int small) {
    float t = (float)big * (63.0f / 511.0f);
    int i0 = (int)t;
    float fr = t - (float)i0;
    int i1 = i0 + 1; if (i1 > 63) i1 = 63;
    float w = 0.0f;
    if (i0 == small) w += 1.0f - fr;
    if (i1 == small) w += fr;
    return w;
}

__device__ __forceinline__ void adj_range(int small, int& lo, int& hi) {
    lo = (int)floorf((small - 1) * (511.0f / 63.0f)); if (lo < 0) lo = 0;
    hi = (int)ceilf((small + 1) * (511.0f / 63.0f));  if (hi > 511) hi = 511;
}

// ---------------------------------------------------------------------------
// seg: 1x1 conv + softmax, ONE pixel per thread (r3 win: 1024 waves =
// 4 waves/CU, all 4 SIMDs busy; serial chain 5376 v_fma vs 21504).
__device__ __forceinline__ void seg_body(int blk, int tid,
                                         const float* __restrict__ fm,
                                         const float* __restrict__ cw,
                                         const float* __restrict__ cb,
                                         float* __restrict__ seg) {
    int gid = blk * 256 + tid;          // 0..65535
    int b   = gid >> 12;                // 4096 px per batch
    int p   = gid & 4095;
    const float* fmb = fm + (size_t)b * FD * SP + p;

    float acc[KN];
#pragma unroll
    for (int k = 0; k < KN; ++k) acc[k] = 0.0f;

#pragma unroll 4
    for (int f = 0; f < FD; ++f) {
        float v = fmb[(size_t)f * SP];   // 256B coalesced per wave
#pragma unroll
        for (int k = 0; k < KN; ++k)
            acc[k] = fmaf(v, cw[k * FD + f], acc[k]);   // cw uniform -> s_load
    }

    float mx = -1e30f;
#pragma unroll
    for (int k = 0; k < KN; ++k) { acc[k] += cb[k]; mx = fmaxf(mx, acc[k]); }
    float s = 0.0f;
#pragma unroll
    for (int k = 0; k < KN; ++k) { acc[k] = expf(acc[k] - mx); s += acc[k]; }
    float inv = 1.0f / s;

    float* segb = seg + (size_t)b * KN * SP + p;
#pragma unroll
    for (int k = 0; k < KN; ++k) segb[(size_t)k * SP] = acc[k] * inv;   // 256B coalesced
}

// downx: tmpA[bc, Y, s] = sum_X W[X,s] * x[bc, Y, X]
// LDS-staged (r4, perf-neutral but transaction-clean): block loads 4 full
// rows (8 KB) with 512 coalesced float4 loads, then gathers from LDS.
__device__ __forceinline__ void downx_body(int blk, int tid,
                                           const float* __restrict__ x,
                                           float* __restrict__ tmpA,
                                           float (*rows)[BW]) {
    int bc = blk >> 7;                  // 0..47
    int Y0 = (blk & 127) << 2;          // 4 Y rows per block
    const f32x4* src = (const f32x4*)(x + ((size_t)bc * BH + Y0) * BW);
    f32x4* dst = (f32x4*)&rows[0][0];
    dst[tid]       = src[tid];          // 2048 floats = 512 float4, 2/thread
    dst[tid + 256] = src[tid + 256];
    __syncthreads();

    int s  = tid & 63;
    int yl = tid >> 6;
    int lo, hi; adj_range(s, lo, hi);
    float acc = 0.0f;
    for (int X = lo; X <= hi; ++X) acc = fmaf(adj_w(X, s), rows[yl][X], acc);
    tmpA[((size_t)bc * BH + Y0 + yl) * SW + s] = acc;   // 256B coalesced
}

// Phase 1: seg (blocks [0,256)) runs concurrently with downx (blocks [256,6400))
__global__ __launch_bounds__(256) void k_phase1(const float* __restrict__ fm,
                                                const float* __restrict__ cw,
                                                const float* __restrict__ cb,
                                                const float* __restrict__ x,
                                                float* __restrict__ seg,
                                                float* __restrict__ tmpA) {
    __shared__ float rows[4][BW];       // 8 KB (unused by seg blocks)
    if (blockIdx.x < SEG_BLOCKS) seg_body(blockIdx.x, threadIdx.x, fm, cw, cb, seg);
    else                         downx_body(blockIdx.x - SEG_BLOCKS, threadIdx.x, x, tmpA, rows);
}

// ---------------------------------------------------------------------------
// downy: xd[bc, r, s] = sum_Y W[Y,r] * tmpA[bc, Y, s]  (f32 W; first 4
// blocks zero q for k_q's atomic accumulation — kernel boundary orders it).
__global__ __launch_bounds__(256) void k_downy(const float* __restrict__ tmpA,
                                               float* __restrict__ xd,
                                               float* __restrict__ q) {
    if (blockIdx.x < 4) {
        int i = blockIdx.x * 256 + threadIdx.x;
        if (i < BN * KN * 3) q[i] = 0.0f;
    }
    int gid = blockIdx.x * 256 + threadIdx.x;   // ((bc)*SH + r)*SW + s
    int s  = gid & 63;
    int r  = (gid >> 6) & 63;
    int bc = gid >> 12;                          // 0..47
    const float* base = tmpA + (size_t)bc * BH * SW + s;
    int lo, hi; adj_range(r, lo, hi);
    float acc = 0.0f;
    for (int Y = lo; Y <= hi; ++Y) acc = fmaf(adj_w(Y, r), base[(size_t)Y * SW], acc);
    xd[gid] = acc;
}

// ---------------------------------------------------------------------------
// q[b,k,c] = (1/BP) * sum_p seg[b,k,p] * xd[b,c,p]
// QSPLIT=4 blocks per (b,k) (r3 win): wave shfl-reduce of just 3 values +
// 3 atomicAdds. (r5's fused variant reduced 63 values/thread — 378 shfls —
// and regressed +15 µs; do not re-fuse.)
__global__ __launch_bounds__(256) void k_q(const float* __restrict__ seg,
                                           const float* __restrict__ xd,
                                           float* __restrict__ q) {
    int bk   = blockIdx.x / QSPLIT;
    int part = blockIdx.x % QSPLIT;
    int b = bk / KN, k = bk % KN;
    const float* sg = seg + ((size_t)b * KN + k) * SP;
    const float* xb = xd + (size_t)b * 3 * SP;
    float a0 = 0.f, a1 = 0.f, a2 = 0.f;
    int p0 = part * (SP / QSPLIT);
    for (int p = p0 + threadIdx.x; p < p0 + SP / QSPLIT; p += 256) {
        float sv = sg[p];
        a0 = fmaf(sv, xb[p], a0);
        a1 = fmaf(sv, xb[SP + p], a1);
        a2 = fmaf(sv, xb[2 * SP + p], a2);
    }
    for (int off = 32; off > 0; off >>= 1) {
        a0 += __shfl_down(a0, off, 64);
        a1 += __shfl_down(a1, off, 64);
        a2 += __shfl_down(a2, off, 64);
    }
    __shared__ float red[4][3];
    int lane = threadIdx.x & 63, w = threadIdx.x >> 6;
    if (lane == 0) { red[w][0] = a0; red[w][1] = a1; red[w][2] = a2; }
    __syncthreads();
    if (threadIdx.x == 0) {
        const float scale = 1.0f / (float)BP;
        float s0 = red[0][0] + red[1][0] + red[2][0] + red[3][0];
        float s1 = red[0][1] + red[1][1] + red[2][1] + red[3][1];
        float s2 = red[0][2] + red[1][2] + red[2][2] + red[3][2];
        float* qo = q + ((size_t)b * KN + k) * 3;
        atomicAdd(qo + 0, s0 * scale);
        atomicAdd(qo + 1, s1 * scale);
        atomicAdd(qo + 2, s2 * scale);
    }
}

// ---------------------------------------------------------------------------
// attn[b,k,p] = sum_c x[b,c,p] * q[b,k,c]; float4, nontemporal stores
__global__ __launch_bounds__(256) void k_attn(const float* __restrict__ x,
                                              const float* __restrict__ q,
                                              float* __restrict__ out) {
    int b   = blockIdx.x >> 8;
    int blk = blockIdx.x & 255;
    int p4  = blk * 256 + threadIdx.x;

    const f32x4* xb = (const f32x4*)(x + (size_t)b * 3 * BP);
    f32x4 x0 = xb[p4];
    f32x4 x1 = xb[BP / 4 + p4];
    f32x4 x2 = xb[2 * (BP / 4) + p4];

    __shared__ float qs[KN * 3];
    if (threadIdx.x < KN * 3) qs[threadIdx.x] = q[(size_t)b * KN * 3 + threadIdx.x];
    __syncthreads();

    f32x4* ob = (f32x4*)(out + (size_t)b * KN * BP) + p4;
#pragma unroll
    for (int k = 0; k < KN; ++k) {
        float q0 = qs[k * 3], q1 = qs[k * 3 + 1], q2 = qs[k * 3 + 2];
        f32x4 r = x0 * q0 + x1 * q1 + x2 * q2;
        __builtin_nontemporal_store(r, ob + (size_t)k * (BP / 4));
    }
}

// ---------------------------------------------------------------------------
extern "C" void kernel_launch(void* const* d_in, const int* in_sizes, int n_in,
                              void* d_out, int out_size, void* d_ws, size_t ws_size,
                              hipStream_t stream) {
    const float* fm = (const float*)d_in[0];   // [16,256,64,64]
    const float* x  = (const float*)d_in[1];   // [16,3,512,512]
    const float* cw = (const float*)d_in[2];   // [21,256]
    const float* cb = (const float*)d_in[3];   // [21]
    float* out = (float*)d_out;                // [16,21,512,512]

    // workspace layout (floats): seg | tmpA | xd | q  (~12.6 MB total)
    float* seg  = (float*)d_ws;                       // 16*21*4096
    float* tmpA = seg  + (size_t)BN * KN * SP;        // 16*3*512*64
    float* xd   = tmpA + (size_t)BN * 3 * BH * SW;    // 16*3*4096
    float* q    = xd   + (size_t)BN * 3 * SP;         // 16*21*3

    k_phase1<<<SEG_BLOCKS + DOWNX_BLOCKS, 256, 0, stream>>>(fm, cw, cb, x, seg, tmpA);
    k_downy <<<BN * 3 * SP / 256,         256, 0, stream>>>(tmpA, xd, q);
    k_q     <<<BN * KN * QSPLIT,          256, 0, stream>>>(seg, xd, q);
    k_attn  <<<BN * (BP / 1024),          256, 0, stream>>>(x, q, out);
}